// Round 21
// baseline (443.428 us; speedup 1.0000x reference)
//
#include <hip/hip_runtime.h>
#include <hip/hip_fp16.h>

#define N_NODES 50000
#define DIM 64
#define EDGE_DIM 32
#define HEADS 8
#define EXP_HEADS 16
#define NEDGE 800000
#define SCALE 0.35355339059327373f  /* 8^-0.5 */
#define EPS 1e-16f
#define NEG_BIG -1e30f
#define NB_SCAN ((N_NODES + 255) / 256)   /* 196 */

#define RFL(x) __builtin_amdgcn_readfirstlane(x)

__device__ __forceinline__ float h2f(unsigned short u) {
    __half h;
    *reinterpret_cast<unsigned short*>(&h) = u;
    return __half2float(h);
}
__device__ __forceinline__ unsigned short f2h(float f) {
    __half h = __float2half(f);
    return *reinterpret_cast<unsigned short*>(&h);
}

// single-exp online softmax update: s,m <- merge(c)
__device__ __forceinline__ void online_upd(float& m, float& s, float c) {
    float mn = fmaxf(m, c);
    float e  = __expf(fminf(m, c) - mn);
    s = (c > m) ? fmaf(s, e, 1.f) : (s + e);
    m = mn;
}

// ---- Kernel A: q,kh,v,vh = x @ {Wq,Wk,Wv}; k stored fp16 only --------------
__global__ __launch_bounds__(256) void qkv_kernel(
    const float* __restrict__ x, const float* __restrict__ Wq,
    const float* __restrict__ Wk, const float* __restrict__ Wv,
    float* __restrict__ q, unsigned short* __restrict__ kh,
    float* __restrict__ v, unsigned short* __restrict__ vh) {
    int gid = blockIdx.x * 256 + threadIdx.x;
    if (gid >= (N_NODES / 4) * DIM) return;
    int quad = gid >> 6, j = gid & 63;
    long i0 = (long)quad * 4;
    float aq[4] = {0,0,0,0}, ak[4] = {0,0,0,0}, av[4] = {0,0,0,0};
#pragma unroll
    for (int l = 0; l < DIM; ++l) {
        float wq = Wq[l * DIM + j], wk = Wk[l * DIM + j], wv = Wv[l * DIM + j];
#pragma unroll
        for (int r = 0; r < 4; ++r) {
            float xv = x[(i0 + r) * DIM + l];
            aq[r] = fmaf(xv, wq, aq[r]);
            ak[r] = fmaf(xv, wk, ak[r]);
            av[r] = fmaf(xv, wv, av[r]);
        }
    }
#pragma unroll
    for (int r = 0; r < 4; ++r) {
        q[(i0 + r) * DIM + j] = aq[r];
        kh[(i0 + r) * DIM + j] = f2h(ak[r]);
        v[(i0 + r) * DIM + j] = av[r];
        vh[(i0 + r) * DIM + j] = f2h(av[r]);
    }
}

// ---- CSR build: histogram --------------------------------------------------
__global__ __launch_bounds__(256) void hist_kernel(
    const int* __restrict__ eidx, unsigned* __restrict__ cnt) {
    int e = blockIdx.x * 256 + threadIdx.x;
    if (e >= NEDGE) return;
    atomicAdd(&cnt[eidx[e]], 1u);
}

// ---- CSR build: 3-phase multi-block exclusive scan -------------------------
__global__ __launch_bounds__(256) void scan_reduce(
    const unsigned* __restrict__ cnt, unsigned* __restrict__ blocksum) {
    int gid = blockIdx.x * 256 + threadIdx.x;
    unsigned v = (gid < N_NODES) ? cnt[gid] : 0u;
    v += __shfl_xor(v, 1);  v += __shfl_xor(v, 2);
    v += __shfl_xor(v, 4);  v += __shfl_xor(v, 8);
    v += __shfl_xor(v, 16); v += __shfl_xor(v, 32);
    __shared__ unsigned ws4[4];
    if ((threadIdx.x & 63) == 0) ws4[threadIdx.x >> 6] = v;
    __syncthreads();
    if (threadIdx.x == 0)
        blocksum[blockIdx.x] = ws4[0] + ws4[1] + ws4[2] + ws4[3];
}

__global__ __launch_bounds__(256) void scan_base(
    const unsigned* __restrict__ blocksum, unsigned* __restrict__ blockbase) {
    __shared__ unsigned ps[256];
    int t = threadIdx.x;
    unsigned v = (t < NB_SCAN) ? blocksum[t] : 0u;
    ps[t] = v;
    __syncthreads();
    for (int off = 1; off < 256; off <<= 1) {
        unsigned val = (t >= off) ? ps[t - off] : 0u;
        __syncthreads();
        ps[t] += val;
        __syncthreads();
    }
    blockbase[t] = ps[t] - v;   // exclusive
}

__global__ __launch_bounds__(256) void scan_final(
    const unsigned* __restrict__ cnt, const unsigned* __restrict__ blockbase,
    unsigned* __restrict__ offsets, unsigned* __restrict__ cursor) {
    __shared__ unsigned ps[256];
    int t = threadIdx.x;
    int gid = blockIdx.x * 256 + t;
    unsigned v = (gid < N_NODES) ? cnt[gid] : 0u;
    ps[t] = v;
    __syncthreads();
    for (int off = 1; off < 256; off <<= 1) {
        unsigned val = (t >= off) ? ps[t - off] : 0u;
        __syncthreads();
        ps[t] += val;
        __syncthreads();
    }
    unsigned off_ = blockbase[blockIdx.x] + ps[t] - v;
    if (gid < N_NODES) { offsets[gid] = off_; cursor[gid] = off_; }
    if (gid == N_NODES - 1) offsets[N_NODES] = off_ + v;
}

// ---- CSR build: scatter src ids + fp16 edge rows into sorted order ---------
__global__ __launch_bounds__(256) void scatter_kernel(
    const int* __restrict__ eidx, const float4* __restrict__ edges4,
    unsigned* __restrict__ cursor,
    unsigned* __restrict__ iperm, unsigned* __restrict__ srcs,
    unsigned short* __restrict__ esort) {
    int e = blockIdx.x * 256 + threadIdx.x;
    if (e >= NEDGE) return;
    int dst = eidx[e];
    unsigned pos = atomicAdd(&cursor[dst], 1u);
    iperm[e] = pos;
    srcs[pos] = (unsigned)eidx[NEDGE + e];
    const float4* src = edges4 + (long)e * 8;           // 32 floats
    ushort4* dst4 = (ushort4*)(esort + (long)pos * EDGE_DIM);
#pragma unroll
    for (int i = 0; i < 8; ++i) {
        float4 t = src[i];
        ushort4 o;
        o.x = f2h(t.x); o.y = f2h(t.y); o.z = f2h(t.z); o.w = f2h(t.w);
        dst4[i] = o;
    }
}

// ---- Kernel B: head logits + ONLINE softmax stats (node-parallel) ----------
// logit8[slot][h] = (q[n,h]·kh[src,h] + esort[slot]·G[n,h,:]) * invt
// Wexp butterfly (xor 8/16/32) gives a[2d],a[2d+1]; single-exp online (m,s).
__global__ __launch_bounds__(256) void edge_attn_kernel(
    const unsigned short* __restrict__ esort,
    const float* __restrict__ q, const unsigned short* __restrict__ kh,
    const float* __restrict__ Wek, const float* __restrict__ Wexp,
    const float* __restrict__ temp,
    const unsigned* __restrict__ offsets, const unsigned* __restrict__ srcs,
    float* __restrict__ logit8, float2* __restrict__ stats2) {
    int tid = threadIdx.x;
    int w = tid >> 6, lane = tid & 63;
    int h = lane >> 3, d = lane & 7;
    float wekr[4][8];
#pragma unroll
    for (int j = 0; j < 4; ++j)
#pragma unroll
        for (int i = 0; i < 8; ++i)
            wekr[j][i] = Wek[(d * 4 + j) * DIM + h * 8 + i];
    float we0 = Wexp[h * EXP_HEADS + 2 * d];
    float we1 = Wexp[h * EXP_HEADS + 2 * d + 1];
    float invt = SCALE / temp[0];
    int n = blockIdx.x * 4 + w;    // N_NODES % 4 == 0, grid exact
    unsigned nb = offsets[n];
    int deg = (int)(offsets[n + 1] - nb);
    const float* __restrict__ qp = q + (long)n * DIM;
    float qreg = qp[lane];
    float qv[8];
#pragma unroll
    for (int t = 0; t < 8; ++t) qv[t] = qp[h * 8 + t];
    float g0 = 0.f, g1 = 0.f, g2 = 0.f, g3 = 0.f;
#pragma unroll
    for (int t = 0; t < 8; ++t) {
        g0 = fmaf(qv[t], wekr[0][t], g0);
        g1 = fmaf(qv[t], wekr[1][t], g1);
        g2 = fmaf(qv[t], wekr[2][t], g2);
        g3 = fmaf(qv[t], wekr[3][t], g3);
    }
    float m0 = NEG_BIG, s0 = 0.f, m1 = NEG_BIG, s1 = 0.f;
    int j = 0;
    for (; j + 4 <= deg; j += 4) {
        float p[4];
#pragma unroll
        for (int g2i = 0; g2i < 4; ++g2i) {
            long slot = (long)nb + j + g2i;
            int s_g = RFL((int)srcs[slot]);
            float kv = h2f(kh[(long)s_g * DIM + lane]);
            ushort4 ue = *(const ushort4*)(esort + slot * EDGE_DIM + d * 4);
            float pp = qreg * kv;
            pp = fmaf(g0, h2f(ue.x), pp);
            pp = fmaf(g1, h2f(ue.y), pp);
            pp = fmaf(g2, h2f(ue.z), pp);
            pp = fmaf(g3, h2f(ue.w), pp);
            p[g2i] = pp;
        }
#pragma unroll
        for (int i = 0; i < 4; ++i) p[i] += __shfl_xor(p[i], 1);
#pragma unroll
        for (int i = 0; i < 4; ++i) p[i] += __shfl_xor(p[i], 2);
#pragma unroll
        for (int i = 0; i < 4; ++i) p[i] += __shfl_xor(p[i], 4);
#pragma unroll
        for (int i = 0; i < 4; ++i) p[i] *= invt;
        if (d == 0) {
#pragma unroll
            for (int i = 0; i < 4; ++i)
                logit8[((long)nb + j + i) * HEADS + h] = p[i];
        }
        // Wexp butterfly + single-exp online stats for two eh per lane
        float c0[4], c1[4];
#pragma unroll
        for (int i = 0; i < 4; ++i) { c0[i] = p[i] * we0; c1[i] = p[i] * we1; }
#pragma unroll
        for (int i = 0; i < 4; ++i) { c0[i] += __shfl_xor(c0[i], 8);  c1[i] += __shfl_xor(c1[i], 8); }
#pragma unroll
        for (int i = 0; i < 4; ++i) { c0[i] += __shfl_xor(c0[i], 16); c1[i] += __shfl_xor(c1[i], 16); }
#pragma unroll
        for (int i = 0; i < 4; ++i) { c0[i] += __shfl_xor(c0[i], 32); c1[i] += __shfl_xor(c1[i], 32); }
#pragma unroll
        for (int i = 0; i < 4; ++i) {
            online_upd(m0, s0, c0[i]);
            online_upd(m1, s1, c1[i]);
        }
    }
    for (; j < deg; ++j) {
        long slot = (long)nb + j;
        int s_g = RFL((int)srcs[slot]);
        float kv = h2f(kh[(long)s_g * DIM + lane]);
        ushort4 ue = *(const ushort4*)(esort + slot * EDGE_DIM + d * 4);
        float pp = qreg * kv;
        pp = fmaf(g0, h2f(ue.x), pp);
        pp = fmaf(g1, h2f(ue.y), pp);
        pp = fmaf(g2, h2f(ue.z), pp);
        pp = fmaf(g3, h2f(ue.w), pp);
        pp += __shfl_xor(pp, 1);
        pp += __shfl_xor(pp, 2);
        pp += __shfl_xor(pp, 4);
        pp *= invt;
        if (d == 0) logit8[slot * HEADS + h] = pp;
        float c0 = pp * we0, c1 = pp * we1;
        c0 += __shfl_xor(c0, 8);  c1 += __shfl_xor(c1, 8);
        c0 += __shfl_xor(c0, 16); c1 += __shfl_xor(c1, 16);
        c0 += __shfl_xor(c0, 32); c1 += __shfl_xor(c1, 32);
        online_upd(m0, s0, c0);
        online_upd(m1, s1, c1);
    }
    if (h == 0) {
        float2 st0; st0.x = m0; st0.y = 1.f / (s0 + EPS);
        float2 st1; st1.x = m1; st1.y = 1.f / (s1 + EPS);
        stats2[(long)n * EXP_HEADS + 2 * d] = st0;
        stats2[(long)n * EXP_HEADS + 2 * d + 1] = st1;
    }
}

// ---- Kernel C: a8 + aggregation (stats precomputed; no pass 1) -------------
__global__ __launch_bounds__(256) void node_fused_kernel(
    const unsigned short* __restrict__ esort,
    const unsigned short* __restrict__ vh,
    const float* __restrict__ v, const float* __restrict__ logit8,
    const unsigned* __restrict__ offsets,
    const unsigned* __restrict__ srcs, const float2* __restrict__ stats2,
    const float* __restrict__ Wexp, const float* __restrict__ Wsq,
    const float* __restrict__ bsq, const float* __restrict__ Wev,
    float* __restrict__ a8s, float* __restrict__ vmagg) {
    int tid = threadIdx.x;
    int w = tid >> 6, lane = tid & 63;
    int g = lane >> 4, t16 = lane & 15;
    int h = lane >> 3, d = lane & 7;
    float we[HEADS];
#pragma unroll
    for (int hh = 0; hh < HEADS; ++hh) we[hh] = Wexp[hh * EXP_HEADS + t16];
    float wsq[HEADS];
#pragma unroll
    for (int j = 0; j < HEADS; ++j) wsq[j] = Wsq[t16 * HEADS + j];
    int hmap = 4 * (t16 & 1) + 2 * ((t16 >> 1) & 1) + ((t16 >> 2) & 1);
    int ih = ((h >> 2) & 1) | (((h >> 1) & 1) << 1) | ((h & 1) << 2);
    float bs_h = bsq[h], bs_w = bsq[hmap];
    bool b0 = (t16 & 1), b1 = (t16 & 2), b2 = (t16 & 4);

    int n = blockIdx.x * 4 + w;    // N_NODES % 4 == 0, grid exact
    unsigned nb = offsets[n];
    int deg = (int)(offsets[n + 1] - nb);

    float2 st = stats2[(long)n * EXP_HEADS + t16];
    float m = st.x, rs = st.y;

    // ---- a8 + aggregation, 4 slots/iter ----
    float acc = 0.f, t0 = 0.f, t1 = 0.f, t2 = 0.f, t3 = 0.f;
    for (int j0 = 0; j0 < deg; j0 += 4) {
        int cnt = deg - j0; if (cnt > 4) cnt = 4;
        const float4* lp = (const float4*)(logit8 + ((long)nb + j0 + g) * HEADS);
        float4 l0 = lp[0], l1 = lp[1];
        float a = l0.x * we[0];
        a = fmaf(l0.y, we[1], a); a = fmaf(l0.z, we[2], a); a = fmaf(l0.w, we[3], a);
        a = fmaf(l1.x, we[4], a); a = fmaf(l1.y, we[5], a);
        a = fmaf(l1.z, we[6], a); a = fmaf(l1.w, we[7], a);
        float p = (g < cnt) ? __expf(a - m) * rs : 0.f;
        float v0 = p * wsq[0], v1 = p * wsq[1], v2 = p * wsq[2], v3 = p * wsq[3];
        float v4 = p * wsq[4], v5 = p * wsq[5], v6 = p * wsq[6], v7 = p * wsq[7];
        float q0, q1, q2, q3, n0, n1, s8;
        q0 = (b0 ? v4 : v0) + __shfl_xor(b0 ? v0 : v4, 1);
        q1 = (b0 ? v5 : v1) + __shfl_xor(b0 ? v1 : v5, 1);
        q2 = (b0 ? v6 : v2) + __shfl_xor(b0 ? v2 : v6, 1);
        q3 = (b0 ? v7 : v3) + __shfl_xor(b0 ? v3 : v7, 1);
        n0 = (b1 ? q2 : q0) + __shfl_xor(b1 ? q0 : q2, 2);
        n1 = (b1 ? q3 : q1) + __shfl_xor(b1 ? q1 : q3, 2);
        s8 = (b2 ? n1 : n0) + __shfl_xor(b2 ? n0 : n1, 4);
        float a8sum = s8 + __shfl_xor(s8, 8);
        if (t16 < 8 && g < cnt)
            a8s[((long)nb + j0 + g) * HEADS + hmap] = a8sum + bs_w;
#pragma unroll
        for (int i = 0; i < 4; ++i) {
            if (i < cnt) {
                long slot = (long)nb + j0 + i;
                int s_g = RFL((int)srcs[slot]);
                float a8 = __shfl(a8sum, i * 16 + ih) + bs_h;
                float vv = h2f(vh[(long)s_g * DIM + lane]);
                ushort4 ue = *(const ushort4*)(esort + slot * EDGE_DIM + d * 4);
                acc = fmaf(a8, vv, acc);
                t0 = fmaf(a8, h2f(ue.x), t0);
                t1 = fmaf(a8, h2f(ue.y), t1);
                t2 = fmaf(a8, h2f(ue.z), t2);
                t3 = fmaf(a8, h2f(ue.w), t3);
            }
        }
    }
    // ev = t[h][:] @ Wev — t[h][l] on lane h*8+(l>>2), reg t_{l&3}
    float ev = 0.f;
#pragma unroll
    for (int l = 0; l < EDGE_DIM; ++l) {
        float tv = ((l & 3) == 0) ? t0 : ((l & 3) == 1) ? t1 : ((l & 3) == 2) ? t2 : t3;
        float tl = __shfl(tv, h * 8 + (l >> 2));
        ev = fmaf(tl, Wev[l * DIM + lane], ev);
    }
    vmagg[(long)n * DIM + lane] = v[(long)n * DIM + lane] - (acc + ev);
}

// ---- transpose a8s (sorted [E,8]) -> attn.T [8,E] via iperm ---------------
__global__ __launch_bounds__(256) void transpose_kernel(
    const float* __restrict__ a8s, const unsigned* __restrict__ iperm,
    float* __restrict__ out2) {
    int e = blockIdx.x * 256 + threadIdx.x;
    if (e >= NEDGE) return;
    long sj = iperm[e];
    const float4* p = (const float4*)(a8s + sj * HEADS);
    float4 lo = p[0], hi = p[1];
    out2[0L * NEDGE + e] = lo.x; out2[1L * NEDGE + e] = lo.y;
    out2[2L * NEDGE + e] = lo.z; out2[3L * NEDGE + e] = lo.w;
    out2[4L * NEDGE + e] = hi.x; out2[5L * NEDGE + e] = hi.y;
    out2[6L * NEDGE + e] = hi.z; out2[7L * NEDGE + e] = hi.w;
}

// ---- Kernel E: out = vmagg @ Wout + bout, 4 nodes per thread ---------------
__global__ __launch_bounds__(256) void out_kernel(
    const float* __restrict__ vmagg, const float* __restrict__ Wout,
    const float* __restrict__ bout, float* __restrict__ out) {
    int gid = blockIdx.x * 256 + threadIdx.x;
    if (gid >= (N_NODES / 4) * DIM) return;
    int quad = gid >> 6, j = gid & 63;
    long i0 = (long)quad * 4;
    float b = bout[j];
    float ac[4] = {b, b, b, b};
#pragma unroll
    for (int l = 0; l < DIM; ++l) {
        float wv = Wout[l * DIM + j];
#pragma unroll
        for (int r = 0; r < 4; ++r)
            ac[r] = fmaf(vmagg[(i0 + r) * DIM + l], wv, ac[r]);
    }
#pragma unroll
    for (int r = 0; r < 4; ++r) out[(i0 + r) * DIM + j] = ac[r];
}

extern "C" void kernel_launch(void* const* d_in, const int* in_sizes, int n_in,
                              void* d_out, int out_size, void* d_ws, size_t ws_size,
                              hipStream_t stream) {
    const float* x     = (const float*)d_in[0];
    const float* edges = (const float*)d_in[1];
    const int*   eidx  = (const int*)d_in[2];
    const float* Wq    = (const float*)d_in[3];
    const float* Wk    = (const float*)d_in[4];
    const float* Wv    = (const float*)d_in[5];
    const float* Wek   = (const float*)d_in[6];
    const float* Wev   = (const float*)d_in[7];
    const float* Wexp  = (const float*)d_in[8];
    const float* Wsq   = (const float*)d_in[9];
    const float* bsq   = (const float*)d_in[10];
    const float* Wout  = (const float*)d_in[11];
    const float* bout  = (const float*)d_in[12];
    const float* temp  = (const float*)d_in[13];

    float* ws = (float*)d_ws;
    // layout in float-words
    float* q       = ws;                        // [0, 3.2M)
    unsigned short* kh = (unsigned short*)(ws + 3200000L);  // [3.2M, 4.8M)
    float* v       = ws + 6400000L;             // [6.4M, 9.6M)
    float* logit8  = ws + 9600000L;             // [9.6M, 16.0M)  E*8
    float* vmagg   = ws + 16000000L;            // [16.0M, 19.2M)
    float* a8s     = q;                         // aliases q..kh (dead after edge_attn)
    unsigned* iperm     = (unsigned*)(ws + 19200000L);  // 800k
    unsigned* srcs      = iperm + NEDGE;                // 800k
    unsigned* cnt       = srcs + NEDGE;                 // 50k
    unsigned* offsets   = cnt + N_NODES;                // 50001
    unsigned* cursor    = offsets + N_NODES + 1;        // 50k
    unsigned* blocksum  = cursor + N_NODES;             // 256
    unsigned* blockbase = blocksum + 256;               // 256
    unsigned short* esort = (unsigned short*)(ws + 21800000L);  // E*32 halves
    unsigned short* vh    = (unsigned short*)(ws + 34600000L);  // N*64 halves -> ends 36.2M
    float2* stats2 = (float2*)(ws + 36200000L); // [36.2M, 37.8M) N*16 float2

    hipMemsetAsync(cnt, 0, (size_t)N_NODES * sizeof(unsigned), stream);

    float* out1 = (float*)d_out;               // [N, 64]
    float* out2 = out1 + (long)N_NODES * DIM;  // [8, E]

    qkv_kernel<<<(N_NODES / 4 * DIM + 255) / 256, 256, 0, stream>>>(x, Wq, Wk, Wv, q, kh, v, vh);
    hist_kernel<<<(NEDGE + 255) / 256, 256, 0, stream>>>(eidx, cnt);
    scan_reduce<<<NB_SCAN, 256, 0, stream>>>(cnt, blocksum);
    scan_base<<<1, 256, 0, stream>>>(blocksum, blockbase);
    scan_final<<<NB_SCAN, 256, 0, stream>>>(cnt, blockbase, offsets, cursor);
    scatter_kernel<<<(NEDGE + 255) / 256, 256, 0, stream>>>(eidx, (const float4*)edges,
                                                            cursor, iperm, srcs, esort);
    edge_attn_kernel<<<N_NODES / 4, 256, 0, stream>>>(esort, q, kh, Wek, Wexp, temp,
                                                      offsets, srcs, logit8, stats2);
    node_fused_kernel<<<N_NODES / 4, 256, 0, stream>>>(esort, vh, v, logit8, offsets, srcs,
                                                       stats2, Wexp, Wsq, bsq, Wev, a8s, vmagg);
    transpose_kernel<<<(NEDGE + 255) / 256, 256, 0, stream>>>(a8s, iperm, out2);
    out_kernel<<<(N_NODES / 4 * DIM + 255) / 256, 256, 0, stream>>>(vmagg, Wout, bout, out1);
}

// Round 22
// 437.368 us; speedup vs baseline: 1.0139x; 1.0139x over previous
//
#include <hip/hip_runtime.h>
#include <hip/hip_fp16.h>

#define N_NODES 50000
#define DIM 64
#define EDGE_DIM 32
#define HEADS 8
#define EXP_HEADS 16
#define NEDGE 800000
#define SCALE 0.35355339059327373f  /* 8^-0.5 */
#define EPS 1e-16f
#define NEG_BIG -1e30f
#define NB_SCAN ((N_NODES + 255) / 256)   /* 196 */

#define RFL(x) __builtin_amdgcn_readfirstlane(x)

__device__ __forceinline__ float h2f(unsigned short u) {
    __half h;
    *reinterpret_cast<unsigned short*>(&h) = u;
    return __half2float(h);
}
__device__ __forceinline__ unsigned short f2h(float f) {
    __half h = __float2half(f);
    return *reinterpret_cast<unsigned short*>(&h);
}

// ---- Kernel A: q,kh,v,vh = x @ {Wq,Wk,Wv}; k stored fp16 only --------------
__global__ __launch_bounds__(256) void qkv_kernel(
    const float* __restrict__ x, const float* __restrict__ Wq,
    const float* __restrict__ Wk, const float* __restrict__ Wv,
    float* __restrict__ q, unsigned short* __restrict__ kh,
    float* __restrict__ v, unsigned short* __restrict__ vh) {
    int gid = blockIdx.x * 256 + threadIdx.x;
    if (gid >= (N_NODES / 4) * DIM) return;
    int quad = gid >> 6, j = gid & 63;
    long i0 = (long)quad * 4;
    float aq[4] = {0,0,0,0}, ak[4] = {0,0,0,0}, av[4] = {0,0,0,0};
#pragma unroll
    for (int l = 0; l < DIM; ++l) {
        float wq = Wq[l * DIM + j], wk = Wk[l * DIM + j], wv = Wv[l * DIM + j];
#pragma unroll
        for (int r = 0; r < 4; ++r) {
            float xv = x[(i0 + r) * DIM + l];
            aq[r] = fmaf(xv, wq, aq[r]);
            ak[r] = fmaf(xv, wk, ak[r]);
            av[r] = fmaf(xv, wv, av[r]);
        }
    }
#pragma unroll
    for (int r = 0; r < 4; ++r) {
        q[(i0 + r) * DIM + j] = aq[r];
        kh[(i0 + r) * DIM + j] = f2h(ak[r]);
        v[(i0 + r) * DIM + j] = av[r];
        vh[(i0 + r) * DIM + j] = f2h(av[r]);
    }
}

// ---- CSR build: histogram --------------------------------------------------
__global__ __launch_bounds__(256) void hist_kernel(
    const int* __restrict__ eidx, unsigned* __restrict__ cnt) {
    int e = blockIdx.x * 256 + threadIdx.x;
    if (e >= NEDGE) return;
    atomicAdd(&cnt[eidx[e]], 1u);
}

// ---- CSR build: 3-phase multi-block exclusive scan -------------------------
__global__ __launch_bounds__(256) void scan_reduce(
    const unsigned* __restrict__ cnt, unsigned* __restrict__ blocksum) {
    int gid = blockIdx.x * 256 + threadIdx.x;
    unsigned v = (gid < N_NODES) ? cnt[gid] : 0u;
    v += __shfl_xor(v, 1);  v += __shfl_xor(v, 2);
    v += __shfl_xor(v, 4);  v += __shfl_xor(v, 8);
    v += __shfl_xor(v, 16); v += __shfl_xor(v, 32);
    __shared__ unsigned ws4[4];
    if ((threadIdx.x & 63) == 0) ws4[threadIdx.x >> 6] = v;
    __syncthreads();
    if (threadIdx.x == 0)
        blocksum[blockIdx.x] = ws4[0] + ws4[1] + ws4[2] + ws4[3];
}

__global__ __launch_bounds__(256) void scan_base(
    const unsigned* __restrict__ blocksum, unsigned* __restrict__ blockbase) {
    __shared__ unsigned ps[256];
    int t = threadIdx.x;
    unsigned v = (t < NB_SCAN) ? blocksum[t] : 0u;
    ps[t] = v;
    __syncthreads();
    for (int off = 1; off < 256; off <<= 1) {
        unsigned val = (t >= off) ? ps[t - off] : 0u;
        __syncthreads();
        ps[t] += val;
        __syncthreads();
    }
    blockbase[t] = ps[t] - v;   // exclusive
}

__global__ __launch_bounds__(256) void scan_final(
    const unsigned* __restrict__ cnt, const unsigned* __restrict__ blockbase,
    unsigned* __restrict__ offsets, unsigned* __restrict__ cursor) {
    __shared__ unsigned ps[256];
    int t = threadIdx.x;
    int gid = blockIdx.x * 256 + t;
    unsigned v = (gid < N_NODES) ? cnt[gid] : 0u;
    ps[t] = v;
    __syncthreads();
    for (int off = 1; off < 256; off <<= 1) {
        unsigned val = (t >= off) ? ps[t - off] : 0u;
        __syncthreads();
        ps[t] += val;
        __syncthreads();
    }
    unsigned off_ = blockbase[blockIdx.x] + ps[t] - v;
    if (gid < N_NODES) { offsets[gid] = off_; cursor[gid] = off_; }
    if (gid == N_NODES - 1) offsets[N_NODES] = off_ + v;
}

// ---- CSR build: scatter src ids + fp16 edge rows into sorted order ---------
__global__ __launch_bounds__(256) void scatter_kernel(
    const int* __restrict__ eidx, const float4* __restrict__ edges4,
    unsigned* __restrict__ cursor,
    unsigned* __restrict__ iperm, unsigned* __restrict__ srcs,
    unsigned short* __restrict__ esort) {
    int e = blockIdx.x * 256 + threadIdx.x;
    if (e >= NEDGE) return;
    int dst = eidx[e];
    unsigned pos = atomicAdd(&cursor[dst], 1u);
    iperm[e] = pos;
    srcs[pos] = (unsigned)eidx[NEDGE + e];
    const float4* src = edges4 + (long)e * 8;           // 32 floats
    ushort4* dst4 = (ushort4*)(esort + (long)pos * EDGE_DIM);
#pragma unroll
    for (int i = 0; i < 8; ++i) {
        float4 t = src[i];
        ushort4 o;
        o.x = f2h(t.x); o.y = f2h(t.y); o.z = f2h(t.z); o.w = f2h(t.w);
        dst4[i] = o;
    }
}

// ---- Kernel B: head logits, NODE-parallel, fp16 operands (fp32 math) -------
// logit8[slot][h] = (q[n,h]·kh[src,h] + esort[slot]·G[n,h,:]) * SCALE/temp
__global__ __launch_bounds__(256) void edge_attn_kernel(
    const unsigned short* __restrict__ esort,
    const float* __restrict__ q, const unsigned short* __restrict__ kh,
    const float* __restrict__ Wek,
    const float* __restrict__ temp,
    const unsigned* __restrict__ offsets, const unsigned* __restrict__ srcs,
    float* __restrict__ logit8) {
    int tid = threadIdx.x;
    int w = tid >> 6, lane = tid & 63;
    int h = lane >> 3, d = lane & 7;
    float wekr[4][8];
#pragma unroll
    for (int j = 0; j < 4; ++j)
#pragma unroll
        for (int i = 0; i < 8; ++i)
            wekr[j][i] = Wek[(d * 4 + j) * DIM + h * 8 + i];
    float invt = SCALE / temp[0];
    int n = blockIdx.x * 4 + w;    // N_NODES % 4 == 0, grid exact
    unsigned nb = offsets[n];
    int deg = (int)(offsets[n + 1] - nb);
    const float* __restrict__ qp = q + (long)n * DIM;
    float qreg = qp[lane];
    float qv[8];
#pragma unroll
    for (int t = 0; t < 8; ++t) qv[t] = qp[h * 8 + t];
    float g0 = 0.f, g1 = 0.f, g2 = 0.f, g3 = 0.f;
#pragma unroll
    for (int t = 0; t < 8; ++t) {
        g0 = fmaf(qv[t], wekr[0][t], g0);
        g1 = fmaf(qv[t], wekr[1][t], g1);
        g2 = fmaf(qv[t], wekr[2][t], g2);
        g3 = fmaf(qv[t], wekr[3][t], g3);
    }
    int j = 0;
    for (; j + 4 <= deg; j += 4) {
        float p[4];
#pragma unroll
        for (int g2i = 0; g2i < 4; ++g2i) {
            long slot = (long)nb + j + g2i;
            int s_g = RFL((int)srcs[slot]);
            float kv = h2f(kh[(long)s_g * DIM + lane]);
            ushort4 ue = *(const ushort4*)(esort + slot * EDGE_DIM + d * 4);
            float pp = qreg * kv;
            pp = fmaf(g0, h2f(ue.x), pp);
            pp = fmaf(g1, h2f(ue.y), pp);
            pp = fmaf(g2, h2f(ue.z), pp);
            pp = fmaf(g3, h2f(ue.w), pp);
            p[g2i] = pp;
        }
#pragma unroll
        for (int i = 0; i < 4; ++i) p[i] += __shfl_xor(p[i], 1);
#pragma unroll
        for (int i = 0; i < 4; ++i) p[i] += __shfl_xor(p[i], 2);
#pragma unroll
        for (int i = 0; i < 4; ++i) p[i] += __shfl_xor(p[i], 4);
        if (d == 0) {
#pragma unroll
            for (int i = 0; i < 4; ++i)
                logit8[((long)nb + j + i) * HEADS + h] = p[i] * invt;
        }
    }
    for (; j < deg; ++j) {
        long slot = (long)nb + j;
        int s_g = RFL((int)srcs[slot]);
        float kv = h2f(kh[(long)s_g * DIM + lane]);
        ushort4 ue = *(const ushort4*)(esort + slot * EDGE_DIM + d * 4);
        float pp = qreg * kv;
        pp = fmaf(g0, h2f(ue.x), pp);
        pp = fmaf(g1, h2f(ue.y), pp);
        pp = fmaf(g2, h2f(ue.z), pp);
        pp = fmaf(g3, h2f(ue.w), pp);
        pp += __shfl_xor(pp, 1);
        pp += __shfl_xor(pp, 2);
        pp += __shfl_xor(pp, 4);
        if (d == 0) logit8[slot * HEADS + h] = pp * invt;
    }
}

// ---- Kernel C: fused softmax stats + a8 + aggregation (R15 4-slot body) ----
__global__ __launch_bounds__(256) void node_fused_kernel(
    const unsigned short* __restrict__ esort,
    const unsigned short* __restrict__ vh,
    const float* __restrict__ v, const float* __restrict__ logit8,
    const unsigned* __restrict__ offsets,
    const unsigned* __restrict__ srcs,
    const float* __restrict__ Wexp, const float* __restrict__ Wsq,
    const float* __restrict__ bsq, const float* __restrict__ Wev,
    float* __restrict__ a8s, float* __restrict__ vmagg) {
    int tid = threadIdx.x;
    int w = tid >> 6, lane = tid & 63;
    int g = lane >> 4, t16 = lane & 15;
    int h = lane >> 3, d = lane & 7;
    float we[HEADS];
#pragma unroll
    for (int hh = 0; hh < HEADS; ++hh) we[hh] = Wexp[hh * EXP_HEADS + t16];
    float wsq[HEADS];
#pragma unroll
    for (int j = 0; j < HEADS; ++j) wsq[j] = Wsq[t16 * HEADS + j];
    int hmap = 4 * (t16 & 1) + 2 * ((t16 >> 1) & 1) + ((t16 >> 2) & 1);
    int ih = ((h >> 2) & 1) | (((h >> 1) & 1) << 1) | ((h & 1) << 2);
    float bs_h = bsq[h], bs_w = bsq[hmap];
    bool b0 = (t16 & 1), b1 = (t16 & 2), b2 = (t16 & 4);

    int n = blockIdx.x * 4 + w;    // N_NODES % 4 == 0, grid exact
    unsigned nb = offsets[n];
    int deg = (int)(offsets[n + 1] - nb);

    // ---- pass 1: online softmax stats (m,s) per eh=t16, 4 slots/iter ----
    float m = NEG_BIG, s = 0.f;
    for (int j0 = 0; j0 < deg; j0 += 4) {
        const float4* lp = (const float4*)(logit8 + ((long)nb + j0 + g) * HEADS);
        float4 l0 = lp[0], l1 = lp[1];
        float a = l0.x * we[0];
        a = fmaf(l0.y, we[1], a); a = fmaf(l0.z, we[2], a); a = fmaf(l0.w, we[3], a);
        a = fmaf(l1.x, we[4], a); a = fmaf(l1.y, we[5], a);
        a = fmaf(l1.z, we[6], a); a = fmaf(l1.w, we[7], a);
        if (j0 + g < deg) {
            float mn = fmaxf(m, a);
            s = s * __expf(m - mn) + __expf(a - mn);
            m = mn;
        }
    }
#pragma unroll
    for (int off = 16; off < 64; off <<= 1) {
        float m2 = __shfl_xor(m, off), s2 = __shfl_xor(s, off);
        float mn = fmaxf(m, m2);
        s = s * __expf(m - mn) + s2 * __expf(m2 - mn);
        m = mn;
    }
    float rs = 1.f / (s + EPS);

    // ---- pass 2: a8 + aggregation, 4 slots/iter ----
    float acc = 0.f, t0 = 0.f, t1 = 0.f, t2 = 0.f, t3 = 0.f;
    for (int j0 = 0; j0 < deg; j0 += 4) {
        int cnt = deg - j0; if (cnt > 4) cnt = 4;
        const float4* lp = (const float4*)(logit8 + ((long)nb + j0 + g) * HEADS);
        float4 l0 = lp[0], l1 = lp[1];
        float a = l0.x * we[0];
        a = fmaf(l0.y, we[1], a); a = fmaf(l0.z, we[2], a); a = fmaf(l0.w, we[3], a);
        a = fmaf(l1.x, we[4], a); a = fmaf(l1.y, we[5], a);
        a = fmaf(l1.z, we[6], a); a = fmaf(l1.w, we[7], a);
        float p = (g < cnt) ? __expf(a - m) * rs : 0.f;
        float v0 = p * wsq[0], v1 = p * wsq[1], v2 = p * wsq[2], v3 = p * wsq[3];
        float v4 = p * wsq[4], v5 = p * wsq[5], v6 = p * wsq[6], v7 = p * wsq[7];
        float q0, q1, q2, q3, n0, n1, s8;
        q0 = (b0 ? v4 : v0) + __shfl_xor(b0 ? v0 : v4, 1);
        q1 = (b0 ? v5 : v1) + __shfl_xor(b0 ? v1 : v5, 1);
        q2 = (b0 ? v6 : v2) + __shfl_xor(b0 ? v2 : v6, 1);
        q3 = (b0 ? v7 : v3) + __shfl_xor(b0 ? v3 : v7, 1);
        n0 = (b1 ? q2 : q0) + __shfl_xor(b1 ? q0 : q2, 2);
        n1 = (b1 ? q3 : q1) + __shfl_xor(b1 ? q1 : q3, 2);
        s8 = (b2 ? n1 : n0) + __shfl_xor(b2 ? n0 : n1, 4);
        float a8sum = s8 + __shfl_xor(s8, 8);
        if (t16 < 8 && g < cnt)
            a8s[((long)nb + j0 + g) * HEADS + hmap] = a8sum + bs_w;
#pragma unroll
        for (int i = 0; i < 4; ++i) {
            if (i < cnt) {
                long slot = (long)nb + j0 + i;
                int s_g = RFL((int)srcs[slot]);
                float a8 = __shfl(a8sum, i * 16 + ih) + bs_h;
                float vv = h2f(vh[(long)s_g * DIM + lane]);
                ushort4 ue = *(const ushort4*)(esort + slot * EDGE_DIM + d * 4);
                acc = fmaf(a8, vv, acc);
                t0 = fmaf(a8, h2f(ue.x), t0);
                t1 = fmaf(a8, h2f(ue.y), t1);
                t2 = fmaf(a8, h2f(ue.z), t2);
                t3 = fmaf(a8, h2f(ue.w), t3);
            }
        }
    }
    // ev = t[h][:] @ Wev — t[h][l] on lane h*8+(l>>2), reg t_{l&3}
    float ev = 0.f;
#pragma unroll
    for (int l = 0; l < EDGE_DIM; ++l) {
        float tv = ((l & 3) == 0) ? t0 : ((l & 3) == 1) ? t1 : ((l & 3) == 2) ? t2 : t3;
        float tl = __shfl(tv, h * 8 + (l >> 2));
        ev = fmaf(tl, Wev[l * DIM + lane], ev);
    }
    vmagg[(long)n * DIM + lane] = v[(long)n * DIM + lane] - (acc + ev);
}

// ---- transpose a8s (sorted [E,8]) -> attn.T [8,E] via iperm ---------------
__global__ __launch_bounds__(256) void transpose_kernel(
    const float* __restrict__ a8s, const unsigned* __restrict__ iperm,
    float* __restrict__ out2) {
    int e = blockIdx.x * 256 + threadIdx.x;
    if (e >= NEDGE) return;
    long sj = iperm[e];
    const float4* p = (const float4*)(a8s + sj * HEADS);
    float4 lo = p[0], hi = p[1];
    out2[0L * NEDGE + e] = lo.x; out2[1L * NEDGE + e] = lo.y;
    out2[2L * NEDGE + e] = lo.z; out2[3L * NEDGE + e] = lo.w;
    out2[4L * NEDGE + e] = hi.x; out2[5L * NEDGE + e] = hi.y;
    out2[6L * NEDGE + e] = hi.z; out2[7L * NEDGE + e] = hi.w;
}

// ---- Kernel E: out = vmagg @ Wout + bout, 4 nodes per thread ---------------
__global__ __launch_bounds__(256) void out_kernel(
    const float* __restrict__ vmagg, const float* __restrict__ Wout,
    const float* __restrict__ bout, float* __restrict__ out) {
    int gid = blockIdx.x * 256 + threadIdx.x;
    if (gid >= (N_NODES / 4) * DIM) return;
    int quad = gid >> 6, j = gid & 63;
    long i0 = (long)quad * 4;
    float b = bout[j];
    float ac[4] = {b, b, b, b};
#pragma unroll
    for (int l = 0; l < DIM; ++l) {
        float wv = Wout[l * DIM + j];
#pragma unroll
        for (int r = 0; r < 4; ++r)
            ac[r] = fmaf(vmagg[(i0 + r) * DIM + l], wv, ac[r]);
    }
#pragma unroll
    for (int r = 0; r < 4; ++r) out[(i0 + r) * DIM + j] = ac[r];
}

extern "C" void kernel_launch(void* const* d_in, const int* in_sizes, int n_in,
                              void* d_out, int out_size, void* d_ws, size_t ws_size,
                              hipStream_t stream) {
    const float* x     = (const float*)d_in[0];
    const float* edges = (const float*)d_in[1];
    const int*   eidx  = (const int*)d_in[2];
    const float* Wq    = (const float*)d_in[3];
    const float* Wk    = (const float*)d_in[4];
    const float* Wv    = (const float*)d_in[5];
    const float* Wek   = (const float*)d_in[6];
    const float* Wev   = (const float*)d_in[7];
    const float* Wexp  = (const float*)d_in[8];
    const float* Wsq   = (const float*)d_in[9];
    const float* bsq   = (const float*)d_in[10];
    const float* Wout  = (const float*)d_in[11];
    const float* bout  = (const float*)d_in[12];
    const float* temp  = (const float*)d_in[13];

    float* ws = (float*)d_ws;
    // layout in float-words
    float* q       = ws;                        // [0, 3.2M)
    unsigned short* kh = (unsigned short*)(ws + 3200000L);  // [3.2M, 4.8M) halves
    float* v       = ws + 6400000L;             // [6.4M, 9.6M)
    float* logit8  = ws + 9600000L;             // [9.6M, 16.0M)  E*8 used, E*16 region
    float* vmagg   = ws + 16000000L;            // [16.0M, 19.2M)
    float* a8s     = q;                         // aliases q..kh region (dead after edge_attn)
    unsigned* iperm     = (unsigned*)(ws + 19200000L);  // 800k
    unsigned* srcs      = iperm + NEDGE;                // 800k
    unsigned* cnt       = srcs + NEDGE;                 // 50k
    unsigned* offsets   = cnt + N_NODES;                // 50001
    unsigned* cursor    = offsets + N_NODES + 1;        // 50k
    unsigned* blocksum  = cursor + N_NODES;             // 256
    unsigned* blockbase = blocksum + 256;               // 256
    unsigned short* esort = (unsigned short*)(ws + 21800000L);  // E*32 halves (12.8M floats)
    unsigned short* vh    = (unsigned short*)(ws + 34600000L);  // N*64 halves

    hipMemsetAsync(cnt, 0, (size_t)N_NODES * sizeof(unsigned), stream);

    float* out1 = (float*)d_out;               // [N, 64]
    float* out2 = out1 + (long)N_NODES * DIM;  // [8, E]

    qkv_kernel<<<(N_NODES / 4 * DIM + 255) / 256, 256, 0, stream>>>(x, Wq, Wk, Wv, q, kh, v, vh);
    hist_kernel<<<(NEDGE + 255) / 256, 256, 0, stream>>>(eidx, cnt);
    scan_reduce<<<NB_SCAN, 256, 0, stream>>>(cnt, blocksum);
    scan_base<<<1, 256, 0, stream>>>(blocksum, blockbase);
    scan_final<<<NB_SCAN, 256, 0, stream>>>(cnt, blockbase, offsets, cursor);
    scatter_kernel<<<(NEDGE + 255) / 256, 256, 0, stream>>>(eidx, (const float4*)edges,
                                                            cursor, iperm, srcs, esort);
    edge_attn_kernel<<<N_NODES / 4, 256, 0, stream>>>(esort, q, kh, Wek, temp,
                                                      offsets, srcs, logit8);
    node_fused_kernel<<<N_NODES / 4, 256, 0, stream>>>(esort, vh, v, logit8, offsets, srcs,
                                                       Wexp, Wsq, bsq, Wev, a8s, vmagg);
    transpose_kernel<<<(NEDGE + 255) / 256, 256, 0, stream>>>(a8s, iperm, out2);
    out_kernel<<<(N_NODES / 4 * DIM + 255) / 256, 256, 0, stream>>>(vmagg, Wout, bout, out1);
}